// Round 3
// baseline (61.510 us; speedup 1.0000x reference)
//
#include <hip/hip_runtime.h>

#define NCLS 19
#define HWPIX (512 * 512)
#define NB 8
#define ALPHA_C 0.7f
#define BETA_C 0.3f
#define EPS_C 1e-7f
#define L2E 1.44269504088896f

typedef float v2f __attribute__((ext_vector_type(2)));

// Pass 1. vs R2 (theory: pass1 is VALU-bound at ~1400 SIMD-cyc/wave-iter,
// ~37 us floor > 26.6 us memory floor; cut VALU ~2x):
//  - TP via direct gather of x[target] (lines are L1/L2-hot from the main
//    float4 loads) + LDS float atomics into per-class bins. Removes the
//    76 v_cmp + ~152 cndmask/add select chain per quad entirely.
//  - N via LDS int atomics (removes ballot/popc SALU issue pressure).
//  - pixel-pair math as ext_vector float2 so LLVM emits v_pk_{mul,add,fma}_f32
//    (full-rate dual f32): exp-scale muls, denom adds, S-FMAs all halve.
//  - S accumulated with pk_fma directly (per-element p never materialized).
__global__ __launch_bounds__(256, 3) void ftl_reduce(
    const float* __restrict__ x,    // [B, C, H, W]
    const int* __restrict__ tgt,    // [B, H, W]
    float* __restrict__ part,       // [B*PB][3*NCLS]  (S | TP | N)
    int PB) {
  const int b = blockIdx.x / PB;
  const int blk = blockIdx.x % PB;
  const int tid = threadIdx.x;

  __shared__ float sS[NCLS], sTP[NCLS];
  __shared__ int sN[NCLS];
  if (tid < NCLS) { sS[tid] = 0.f; sTP[tid] = 0.f; sN[tid] = 0; }
  __syncthreads();

  const int quadsPerBlock = (HWPIX / 4) / PB;  // PB power of two -> uniform
  const int qbase = blk * quadsPerBlock;
  const float* xb = x + (size_t)b * NCLS * HWPIX;
  const int* tb = tgt + (size_t)b * HWPIX;

  v2f S2[NCLS];
#pragma unroll
  for (int c = 0; c < NCLS; ++c) S2[c] = (v2f){0.f, 0.f};

  for (int q = tid; q < quadsPerBlock; q += 256) {
    const int pix = (qbase + q) * 4;
    const int4 t = *reinterpret_cast<const int4*>(tb + pix);
    // Gather x at the target class early (latency hides under the class loop).
    const float xt0 = xb[(size_t)t.x * HWPIX + pix + 0];
    const float xt1 = xb[(size_t)t.y * HWPIX + pix + 1];
    const float xt2 = xb[(size_t)t.z * HWPIX + pix + 2];
    const float xt3 = xb[(size_t)t.w * HWPIX + pix + 3];

    v2f ea[NCLS], eb[NCLS];
    v2f sea = (v2f){0.f, 0.f}, seb = (v2f){0.f, 0.f};
#pragma unroll
    for (int c = 0; c < NCLS; ++c) {
      const float4 xv = *reinterpret_cast<const float4*>(xb + (size_t)c * HWPIX + pix);
      v2f a = (v2f){xv.x, xv.y} * L2E;   // v_pk_mul_f32
      v2f bb = (v2f){xv.z, xv.w} * L2E;
      ea[c] = (v2f){__builtin_amdgcn_exp2f(a.x), __builtin_amdgcn_exp2f(a.y)};
      eb[c] = (v2f){__builtin_amdgcn_exp2f(bb.x), __builtin_amdgcn_exp2f(bb.y)};
      sea += ea[c];                      // v_pk_add_f32
      seb += eb[c];
    }
    const v2f inva = (v2f){__builtin_amdgcn_rcpf(sea.x), __builtin_amdgcn_rcpf(sea.y)};
    const v2f invb = (v2f){__builtin_amdgcn_rcpf(seb.x), __builtin_amdgcn_rcpf(seb.y)};
#pragma unroll
    for (int c = 0; c < NCLS; ++c)
      S2[c] += ea[c] * inva + eb[c] * invb;   // 2x v_pk_fma_f32

    // TP and N histogram via LDS atomics (LDS pipe, parallel to VALU).
    atomicAdd(&sTP[t.x], __builtin_amdgcn_exp2f(xt0 * L2E) * inva.x);
    atomicAdd(&sTP[t.y], __builtin_amdgcn_exp2f(xt1 * L2E) * inva.y);
    atomicAdd(&sTP[t.z], __builtin_amdgcn_exp2f(xt2 * L2E) * invb.x);
    atomicAdd(&sTP[t.w], __builtin_amdgcn_exp2f(xt3 * L2E) * invb.y);
    atomicAdd(&sN[t.x], 1);
    atomicAdd(&sN[t.y], 1);
    atomicAdd(&sN[t.z], 1);
    atomicAdd(&sN[t.w], 1);
  }

  // Reduce S: fold pair, wave butterfly, wave leaders merge in LDS.
#pragma unroll
  for (int c = 0; c < NCLS; ++c) {
    float Sc = S2[c].x + S2[c].y;
    for (int off = 32; off; off >>= 1) Sc += __shfl_down(Sc, off);
    if ((tid & 63) == 0) atomicAdd(&sS[c], Sc);
  }
  __syncthreads();
  if (tid < NCLS) {
    float* p = part + (size_t)blockIdx.x * (3 * NCLS);
    p[tid] = sS[tid];
    p[NCLS + tid] = sTP[tid];
    p[2 * NCLS + tid] = (float)sN[tid];
  }
}

// Pass 2: one block, 640 threads. Each (b, c) pair (152) owned by 4 lanes;
// each lane sums PB/4 partials, 2-step shfl_xor combines, block-reduce.
__global__ __launch_bounds__(640) void ftl_final(
    const float* __restrict__ part, float* __restrict__ out, int PB) {
  const int tid = threadIdx.x;
  const int pair = tid >> 2;
  const int s = tid & 3;
  float v = 0.f;
  if (pair < NB * NCLS) {
    const int b = pair / NCLS;
    const int c = pair % NCLS;
    float S = 0.f, TP = 0.f, Nc = 0.f;
    for (int p = s; p < PB; p += 4) {
      const float* q = part + (size_t)(b * PB + p) * (3 * NCLS);
      S += q[c];
      TP += q[NCLS + c];
      Nc += q[2 * NCLS + c];
    }
    S += __shfl_xor(S, 1);  S += __shfl_xor(S, 2);
    TP += __shfl_xor(TP, 1); TP += __shfl_xor(TP, 2);
    Nc += __shfl_xor(Nc, 1); Nc += __shfl_xor(Nc, 2);
    if (s == 0) {
      const float FPv = S - TP;
      const float FNv = Nc - TP;
      const float tv = (TP + EPS_C) / (TP + ALPHA_C * FNv + BETA_C * FPv + EPS_C);
      v = 1.0f - tv;  // GAMMA == 1.0
    }
  }
  for (int off = 32; off; off >>= 1) v += __shfl_down(v, off);
  __shared__ float wsum[10];
  if ((tid & 63) == 0) wsum[tid >> 6] = v;
  __syncthreads();
  if (tid == 0) {
    float r = 0.f;
#pragma unroll
    for (int w = 0; w < 10; ++w) r += wsum[w];
    out[0] = r / (float)NB;
  }
}

extern "C" void kernel_launch(void* const* d_in, const int* in_sizes, int n_in,
                              void* d_out, int out_size, void* d_ws, size_t ws_size,
                              hipStream_t stream) {
  const float* x = (const float*)d_in[0];
  const int* tgt = (const int*)d_in[1];
  float* out = (float*)d_out;
  float* part = (float*)d_ws;

  // Largest power-of-two partial count per image that fits the workspace.
  int PB = 128;
  while (PB > 1 && (size_t)(NB * PB * 3 * NCLS * sizeof(float)) > ws_size) PB >>= 1;

  ftl_reduce<<<NB * PB, 256, 0, stream>>>(x, tgt, part, PB);
  ftl_final<<<1, 640, 0, stream>>>(part, out, PB);
}

// Round 4
// 56.358 us; speedup vs baseline: 1.0914x; 1.0914x over previous
//
#include <hip/hip_runtime.h>

#define NCLS 19
#define HWPIX (512 * 512)
#define NB 8
#define ALPHA_C 0.7f
#define BETA_C 0.3f
#define EPS_C 1e-7f
#define L2E 1.44269504088896f

typedef float v2f __attribute__((ext_vector_type(2)));

// Pass 1. Theory: R2 was VALU-bound (~1700 SIMD-cyc/wave-iter ~= 45 us, vs
// ~26 us memory floor). R3 cut VALU the right way (O(1)/pixel histogram) but
// died on single-copy LDS atomic serialization + cold scattered gathers.
// R4 fixes both:
//  - 32-copy LDS bins [NCLS][32], copy = tid&31: bank == copy index, so every
//    histogram atomic is <=2-way bank-aliased (free) and same-address
//    serialization is <=2-way. Histogram rides the LDS pipe under the VALU.
//  - target-class gather issued AFTER the 19 stream loads of the same iter:
//    requests merge in flight / hit L2 (per-XCD iter footprint ~1.8 MB < 4 MB).
//  - all remaining f32 math packed (v_pk_mul/add/fma): ~175x2 + 84x8 cyc
//    ~= 1050 cyc/wave-iter -> VALU floor ~28 us, at parity with memory.
__global__ __launch_bounds__(256, 3) void ftl_reduce(
    const float* __restrict__ x,    // [B, C, H, W]
    const int* __restrict__ tgt,    // [B, H, W]
    float* __restrict__ part,       // [B*PB][3*NCLS]  (S | TP | N)
    int PB) {
  const int b = blockIdx.x / PB;
  const int blk = blockIdx.x % PB;
  const int tid = threadIdx.x;

  __shared__ float sTPb[NCLS][32];
  __shared__ int sNb[NCLS][32];
  __shared__ float sS[NCLS];
  for (int i = tid; i < NCLS * 32; i += 256) {
    (&sTPb[0][0])[i] = 0.f;
    (&sNb[0][0])[i] = 0;
  }
  if (tid < NCLS) sS[tid] = 0.f;
  __syncthreads();

  const int quadsPerBlock = (HWPIX / 4) / PB;  // PB power of two -> uniform
  const int qbase = blk * quadsPerBlock;
  const float* xb = x + (size_t)b * NCLS * HWPIX;
  const int* tb = tgt + (size_t)b * HWPIX;
  const int cp = tid & 31;  // private-ish histogram copy

  v2f S2[NCLS];
#pragma unroll
  for (int c = 0; c < NCLS; ++c) S2[c] = (v2f){0.f, 0.f};

  for (int q = tid; q < quadsPerBlock; q += 256) {
    const int pix = (qbase + q) * 4;
    const int4 t = *reinterpret_cast<const int4*>(tb + pix);

    v2f ea[NCLS], eb[NCLS];
    v2f sea = (v2f){0.f, 0.f}, seb = (v2f){0.f, 0.f};
#pragma unroll
    for (int c = 0; c < NCLS; ++c) {
      const float4 xv = *reinterpret_cast<const float4*>(xb + (size_t)c * HWPIX + pix);
      const v2f a = (v2f){xv.x, xv.y} * L2E;   // v_pk_mul_f32
      const v2f bb = (v2f){xv.z, xv.w} * L2E;
      ea[c] = (v2f){__builtin_amdgcn_exp2f(a.x), __builtin_amdgcn_exp2f(a.y)};
      eb[c] = (v2f){__builtin_amdgcn_exp2f(bb.x), __builtin_amdgcn_exp2f(bb.y)};
      sea += ea[c];                            // v_pk_add_f32
      seb += eb[c];
    }
    const v2f inva = (v2f){__builtin_amdgcn_rcpf(sea.x), __builtin_amdgcn_rcpf(sea.y)};
    const v2f invb = (v2f){__builtin_amdgcn_rcpf(seb.x), __builtin_amdgcn_rcpf(seb.y)};
#pragma unroll
    for (int c = 0; c < NCLS; ++c) {
      S2[c] += ea[c] * inva;                   // v_pk_fma_f32
      S2[c] += eb[c] * invb;
    }

    // Target-class gather: issued after the stream loads so the lines are
    // in-flight/L2-hot. One pixel contributes to exactly one class.
    const v2f xta = (v2f){xb[(size_t)t.x * HWPIX + pix + 0],
                          xb[(size_t)t.y * HWPIX + pix + 1]} * L2E;
    const v2f xtb = (v2f){xb[(size_t)t.z * HWPIX + pix + 2],
                          xb[(size_t)t.w * HWPIX + pix + 3]} * L2E;
    const v2f pta = (v2f){__builtin_amdgcn_exp2f(xta.x),
                          __builtin_amdgcn_exp2f(xta.y)} * inva;
    const v2f ptb = (v2f){__builtin_amdgcn_exp2f(xtb.x),
                          __builtin_amdgcn_exp2f(xtb.y)} * invb;
    atomicAdd(&sTPb[t.x][cp], pta.x);
    atomicAdd(&sTPb[t.y][cp], pta.y);
    atomicAdd(&sTPb[t.z][cp], ptb.x);
    atomicAdd(&sTPb[t.w][cp], ptb.y);
    atomicAdd(&sNb[t.x][cp], 1);
    atomicAdd(&sNb[t.y][cp], 1);
    atomicAdd(&sNb[t.z][cp], 1);
    atomicAdd(&sNb[t.w][cp], 1);
  }

  // Reduce S: fold pair, wave butterfly, wave leaders merge in LDS.
#pragma unroll
  for (int c = 0; c < NCLS; ++c) {
    float Sc = S2[c].x + S2[c].y;
    for (int off = 32; off; off >>= 1) Sc += __shfl_down(Sc, off);
    if ((tid & 63) == 0) atomicAdd(&sS[c], Sc);
  }
  __syncthreads();
  if (tid < NCLS) {
    float tp = 0.f;
    int n = 0;
#pragma unroll
    for (int i = 0; i < 32; ++i) { tp += sTPb[tid][i]; n += sNb[tid][i]; }
    float* p = part + (size_t)blockIdx.x * (3 * NCLS);
    p[tid] = sS[tid];
    p[NCLS + tid] = tp;
    p[2 * NCLS + tid] = (float)n;
  }
}

// Pass 2: one block, 640 threads. Each (b, c) pair (152) owned by 4 lanes;
// each lane sums PB/4 partials, 2-step shfl_xor combines, block-reduce.
__global__ __launch_bounds__(640) void ftl_final(
    const float* __restrict__ part, float* __restrict__ out, int PB) {
  const int tid = threadIdx.x;
  const int pair = tid >> 2;
  const int s = tid & 3;
  float v = 0.f;
  if (pair < NB * NCLS) {
    const int b = pair / NCLS;
    const int c = pair % NCLS;
    float S = 0.f, TP = 0.f, Nc = 0.f;
    for (int p = s; p < PB; p += 4) {
      const float* q = part + (size_t)(b * PB + p) * (3 * NCLS);
      S += q[c];
      TP += q[NCLS + c];
      Nc += q[2 * NCLS + c];
    }
    S += __shfl_xor(S, 1);  S += __shfl_xor(S, 2);
    TP += __shfl_xor(TP, 1); TP += __shfl_xor(TP, 2);
    Nc += __shfl_xor(Nc, 1); Nc += __shfl_xor(Nc, 2);
    if (s == 0) {
      const float FPv = S - TP;
      const float FNv = Nc - TP;
      const float tv = (TP + EPS_C) / (TP + ALPHA_C * FNv + BETA_C * FPv + EPS_C);
      v = 1.0f - tv;  // GAMMA == 1.0
    }
  }
  for (int off = 32; off; off >>= 1) v += __shfl_down(v, off);
  __shared__ float wsum[10];
  if ((tid & 63) == 0) wsum[tid >> 6] = v;
  __syncthreads();
  if (tid == 0) {
    float r = 0.f;
#pragma unroll
    for (int w = 0; w < 10; ++w) r += wsum[w];
    out[0] = r / (float)NB;
  }
}

extern "C" void kernel_launch(void* const* d_in, const int* in_sizes, int n_in,
                              void* d_out, int out_size, void* d_ws, size_t ws_size,
                              hipStream_t stream) {
  const float* x = (const float*)d_in[0];
  const int* tgt = (const int*)d_in[1];
  float* out = (float*)d_out;
  float* part = (float*)d_ws;

  // Largest power-of-two partial count per image that fits the workspace.
  int PB = 128;
  while (PB > 1 && (size_t)(NB * PB * 3 * NCLS * sizeof(float)) > ws_size) PB >>= 1;

  ftl_reduce<<<NB * PB, 256, 0, stream>>>(x, tgt, part, PB);
  ftl_final<<<1, 640, 0, stream>>>(part, out, PB);
}

// Round 5
// 49.415 us; speedup vs baseline: 1.2448x; 1.1405x over previous
//
#include <hip/hip_runtime.h>

#define NCLS 19
#define HWPIX (512 * 512)
#define NB 8
#define PB 64
#define ALPHA_C 0.7f
#define BETA_C 0.3f
#define EPS_C 1e-7f
#define L2E 1.44269504088896f

typedef float v2f __attribute__((ext_vector_type(2)));

// R5: single fused kernel. R1-R4 showed pass-1 is insensitive to occupancy,
// request size, and VALU count (corrected model: only ~8 wave-iters/SIMD ->
// VALU ~6 us, HBM floor ~27 us, measured total 56 us). The unexplained
// ~25 us is suspected launch #2 + inter-kernel drain + single-block pass 2.
// Fuse: each block writes its deterministic partial slice, takes a
// device-scope ticket; the last block re-reads all partials (116 KB) and
// computes the loss. Standard split-K last-block pattern (fence + device
// atomic, valid across XCDs per guide G16).
__global__ __launch_bounds__(256, 3) void ftl_fused(
    const float* __restrict__ x,    // [B, C, H, W]
    const int* __restrict__ tgt,    // [B, H, W]
    float* __restrict__ part,       // [B*PB][3*NCLS]  (S | TP | N)
    int* __restrict__ counter,      // zeroed by hipMemsetAsync pre-launch
    float* __restrict__ out) {
  const int b = blockIdx.x / PB;
  const int blk = blockIdx.x % PB;
  const int tid = threadIdx.x;

  __shared__ float sTPb[NCLS][32];
  __shared__ int sNb[NCLS][32];
  __shared__ float sS[NCLS];
  for (int i = tid; i < NCLS * 32; i += 256) {
    (&sTPb[0][0])[i] = 0.f;
    (&sNb[0][0])[i] = 0;
  }
  if (tid < NCLS) sS[tid] = 0.f;
  __syncthreads();

  const int quadsPerBlock = (HWPIX / 4) / PB;  // 1024
  const int qbase = blk * quadsPerBlock;
  const float* xb = x + (size_t)b * NCLS * HWPIX;
  const int* tb = tgt + (size_t)b * HWPIX;
  const int cp = tid & 31;  // private-ish histogram copy (bank == copy)

  v2f S2[NCLS];
#pragma unroll
  for (int c = 0; c < NCLS; ++c) S2[c] = (v2f){0.f, 0.f};

  for (int q = tid; q < quadsPerBlock; q += 256) {
    const int pix = (qbase + q) * 4;
    const int4 t = *reinterpret_cast<const int4*>(tb + pix);

    v2f ea[NCLS], eb[NCLS];
    v2f sea = (v2f){0.f, 0.f}, seb = (v2f){0.f, 0.f};
#pragma unroll
    for (int c = 0; c < NCLS; ++c) {
      const float4 xv = *reinterpret_cast<const float4*>(xb + (size_t)c * HWPIX + pix);
      const v2f a = (v2f){xv.x, xv.y} * L2E;   // v_pk_mul_f32
      const v2f bb = (v2f){xv.z, xv.w} * L2E;
      ea[c] = (v2f){__builtin_amdgcn_exp2f(a.x), __builtin_amdgcn_exp2f(a.y)};
      eb[c] = (v2f){__builtin_amdgcn_exp2f(bb.x), __builtin_amdgcn_exp2f(bb.y)};
      sea += ea[c];                            // v_pk_add_f32
      seb += eb[c];
    }
    const v2f inva = (v2f){__builtin_amdgcn_rcpf(sea.x), __builtin_amdgcn_rcpf(sea.y)};
    const v2f invb = (v2f){__builtin_amdgcn_rcpf(seb.x), __builtin_amdgcn_rcpf(seb.y)};
#pragma unroll
    for (int c = 0; c < NCLS; ++c) {
      S2[c] += ea[c] * inva;                   // v_pk_fma_f32
      S2[c] += eb[c] * invb;
    }

    // Target-class gather after the stream loads (lines in-flight/L1-hot).
    const v2f xta = (v2f){xb[(size_t)t.x * HWPIX + pix + 0],
                          xb[(size_t)t.y * HWPIX + pix + 1]} * L2E;
    const v2f xtb = (v2f){xb[(size_t)t.z * HWPIX + pix + 2],
                          xb[(size_t)t.w * HWPIX + pix + 3]} * L2E;
    const v2f pta = (v2f){__builtin_amdgcn_exp2f(xta.x),
                          __builtin_amdgcn_exp2f(xta.y)} * inva;
    const v2f ptb = (v2f){__builtin_amdgcn_exp2f(xtb.x),
                          __builtin_amdgcn_exp2f(xtb.y)} * invb;
    atomicAdd(&sTPb[t.x][cp], pta.x);
    atomicAdd(&sTPb[t.y][cp], pta.y);
    atomicAdd(&sTPb[t.z][cp], ptb.x);
    atomicAdd(&sTPb[t.w][cp], ptb.y);
    atomicAdd(&sNb[t.x][cp], 1);
    atomicAdd(&sNb[t.y][cp], 1);
    atomicAdd(&sNb[t.z][cp], 1);
    atomicAdd(&sNb[t.w][cp], 1);
  }

  // Reduce S: fold pair, wave butterfly, wave leaders merge in LDS.
#pragma unroll
  for (int c = 0; c < NCLS; ++c) {
    float Sc = S2[c].x + S2[c].y;
    for (int off = 32; off; off >>= 1) Sc += __shfl_down(Sc, off);
    if ((tid & 63) == 0) atomicAdd(&sS[c], Sc);
  }
  __syncthreads();
  if (tid < NCLS) {
    float tp = 0.f;
    int n = 0;
#pragma unroll
    for (int i = 0; i < 32; ++i) { tp += sTPb[tid][i]; n += sNb[tid][i]; }
    float* p = part + (size_t)blockIdx.x * (3 * NCLS);
    p[tid] = sS[tid];
    p[NCLS + tid] = tp;
    p[2 * NCLS + tid] = (float)n;
  }

  // ---- last-block final reduction ----
  __syncthreads();  // part-slice stores drained (waitcnt before barrier)
  __shared__ int lastFlag;
  if (tid == 0) {
    __threadfence();  // release: make this block's slice device-visible
    lastFlag = (atomicAdd(counter, 1) == (NB * PB - 1));
  }
  __syncthreads();
  if (!lastFlag) return;
  __threadfence();  // acquire: invalidate stale cached partials

  float v = 0.f;
  if (tid < NB * NCLS) {
    const int bb = tid / NCLS;
    const int c = tid % NCLS;
    float S = 0.f, TP = 0.f, Nc = 0.f;
#pragma unroll 16
    for (int p = 0; p < PB; ++p) {
      const float* q = part + (size_t)(bb * PB + p) * (3 * NCLS);
      S += q[c];
      TP += q[NCLS + c];
      Nc += q[2 * NCLS + c];
    }
    const float FPv = S - TP;
    const float FNv = Nc - TP;
    const float tv = (TP + EPS_C) / (TP + ALPHA_C * FNv + BETA_C * FPv + EPS_C);
    v = 1.0f - tv;  // GAMMA == 1.0
  }
  for (int off = 32; off; off >>= 1) v += __shfl_down(v, off);
  __shared__ float wsum[4];
  if ((tid & 63) == 0) wsum[tid >> 6] = v;
  __syncthreads();
  if (tid == 0) out[0] = (wsum[0] + wsum[1] + wsum[2] + wsum[3]) / (float)NB;
}

extern "C" void kernel_launch(void* const* d_in, const int* in_sizes, int n_in,
                              void* d_out, int out_size, void* d_ws, size_t ws_size,
                              hipStream_t stream) {
  const float* x = (const float*)d_in[0];
  const int* tgt = (const int*)d_in[1];
  float* out = (float*)d_out;
  float* part = (float*)d_ws;
  int* counter = (int*)(part + NB * PB * 3 * NCLS);  // right after partials

  hipMemsetAsync(counter, 0, sizeof(int), stream);  // graph-capturable
  ftl_fused<<<NB * PB, 256, 0, stream>>>(x, tgt, part, counter, out);
}